// Round 11
// baseline (201.454 us; speedup 1.0000x reference)
//
#include <hip/hip_runtime.h>
#include <math.h>

#define LATN 721
#define LONN 1440
#define NLEV 13
#define NBATCH 2
#define SLICE (LATN * LONN)              // 1,038,240
#define BATSTRIDE (NLEV * SLICE)

// geometry: thread = 4 output rows x 2 cols (float2); wave = 128 cols, 124 used
#define OUTW 124                         // output cols per wave (lanes 1..62)
#define WGCOLS 496                       // 4 waves
#define SEGS 3                           // ceil(1440/496)
#define NRB 181                          // ceil(721/4) row-blocks
#define NWGX (NRB * SEGS)                // 543

// ---- ws float layout ----
#define NBANK      128
#define BANKSTRIDE 64
#define WS_ACC     0                     // [NBANK*BANKSTRIDE]
#define ACC_SUM    0        // [26] per (b,l) sums
#define ACC_SSQ    26       // [2]  per-batch total sum-of-squares
#define ACC_GRAD   28
#define ACC_MASS   29
#define N_ACC      30
#define WS_INVDX   (NBANK * BANKSTRIDE)          // [721]
#define WS_FCOR    (WS_INVDX + LATN)             // [721]
#define WS_W       (WS_FCOR + LATN)              // [13]
#define WS_INVDP   (WS_W + NLEV)
#define WS_INV2DP  (WS_INVDP + 1)

constexpr float INV_R     = (float)(1.0 / 6371000.0);
constexpr float INV_DLAT  = (float)(720.0 / M_PI);
constexpr float INV_2DLAT = (float)(360.0 / M_PI);
constexpr float INV_DLON  = (float)(1440.0 / (2.0 * M_PI));
constexpr float INV_2DLON = (float)(720.0 / (2.0 * M_PI));
constexpr float QG_COEF   = 1e-4f;   // F0^2 / N^2

// ---------------- setup: row tables, weights, zero accumulators ----------------
__global__ void pl_setup_kernel(const float* __restrict__ plev, float* __restrict__ ws) {
    const int t = threadIdx.x;
    if (t < LATN) {
        double lat;
        if (t == 0)            lat = (double)(-(float)(M_PI / 2.0));
        else if (t == LATN-1)  lat = (double)( (float)(M_PI / 2.0));
        else                   lat = (double)((float)(-M_PI / 2.0 + (double)t * (M_PI / 720.0)));
        double c = cos(lat);
        if (c < 1e-8) c = 1e-8;                      // matches jnp.clip(cos, 1e-8)
        ws[WS_INVDX + t] = (float)(1.0 / (6371000.0 * c));
        ws[WS_FCOR  + t] = (float)(2.0 * 7.292e-05 * sin(lat));
    }
    if (t < NLEV) {
        float p[NLEV];
        #pragma unroll
        for (int l = 0; l < NLEV; ++l) p[l] = plev[l] * 100.0f;
        float dpl[NLEV-1];
        #pragma unroll
        for (int l = 0; l < NLEV-1; ++l) dpl[l] = p[l+1] - p[l];
        float raw;
        if (t == 0)            raw = dpl[0] * 0.5f;
        else if (t == NLEV-1)  raw = dpl[NLEV-2] * 0.5f;
        else                   raw = (dpl[t-1] + dpl[t]) * 0.5f;
        float s = dpl[0] * 0.5f + dpl[NLEV-2] * 0.5f;
        #pragma unroll
        for (int l = 1; l < NLEV-1; ++l) s += (dpl[l-1] + dpl[l]) * 0.5f;
        if (s < 1e-8f) s = 1e-8f;
        ws[WS_W + t] = raw / s;
    }
    if (t == 0) {
        float sd = 0.f;
        for (int l = 0; l < NLEV-1; ++l) sd += plev[l+1] - plev[l];
        float dp = sd / (float)(NLEV-1) * 100.0f;    // mean(diff)*100 (hPa->Pa)
        ws[WS_INVDP]  = 1.0f / dp;
        ws[WS_INV2DP] = 1.0f / (2.0f * dp);
    }
    for (int z = t; z < NBANK * BANKSTRIDE; z += 1024) ws[WS_ACC + z] = 0.0f;
}

// ---------------- helpers ----------------
__device__ __forceinline__ int swz_nwg(int orig, int nwg) {
    // bijective XCD-chunk swizzle (m204)
    const int q = nwg >> 3, r = nwg & 7;
    const int x = orig & 7, k = orig >> 3;
    return (x < r ? x * (q + 1) : r * (q + 1) + (x - r) * q) + k;
}
__device__ __forceinline__ float2 ld2(const float* p) {
    return *reinterpret_cast<const float2*>(p);
}
__device__ __forceinline__ float2 sm2(float2 a, float2 b, float s) {   // (a-b)*s
    return make_float2((a.x - b.x) * s, (a.y - b.y) * s);
}

// ---------------- fused kernel: 4 rows x 2 cols per thread, 6 rolling qg streams ----------------
__launch_bounds__(256)
__global__ void pl_rc42_kernel(const float* __restrict__ u, const float* __restrict__ v,
                               float* __restrict__ ws)
{
    __shared__ float red[16][17];

    const int tid  = threadIdx.x;
    const int lane = tid & 63, w = tid >> 6;
    const int b  = blockIdx.y;
    const int wg = swz_nwg(blockIdx.x, NWGX);
    const int wgr = wg / SEGS, seg = wg - wgr * SEGS;
    const int r0  = 4 * wgr;                         // 0,4,...,720

    // columns: lane owns pair (c0, c0+1); lanes 1..62 are outputs, 0/63 shfl halo
    const int out0  = seg * WGCOLS + w * OUTW;
    const int c0_un = out0 - 2 + 2 * lane;           // even
    const int cb = max(0, min(c0_un, LONN - 2));     // 8B-aligned pair base
    const float m0 = (lane >= 1 && lane <= 62 && c0_un     < LONN) ? 1.f : 0.f;
    const float m1 = (lane >= 1 && lane <= 62 && c0_un + 1 < LONN) ? 1.f : 0.f;
    const bool e0 = (c0_un == 0);                    // .x is col 0 (parity: always .x)
    const bool e1 = (c0_un + 1 == LONN - 1);         // .y is col 1439 (always .y)

    // rows: outputs r0..r0+3; vort rows (streams j=0..5) = r0-1 .. r0+4
    const bool rTop = (r0 == 0), rBot = (r0 == LATN - 1);   // r0==720 only at wgr=180
    const float rv1 = (r0 + 1 < LATN) ? 1.f : 0.f;
    const float rv2 = (r0 + 2 < LATN) ? 1.f : 0.f;
    const float rv3 = (r0 + 3 < LATN) ? 1.f : 0.f;
    const float m10 = m0 * rv1, m11 = m1 * rv1;
    const float m20 = m0 * rv2, m21 = m1 * rv2;
    const float m30 = m0 * rv3, m31 = m1 * rv3;

    // clamped global rows: u streams k=0..7 (r0-2+k), v/vort streams j=0..5 (r0-1+j)
    #define CR(x) max(0, min((x), LATN - 1))
    const int gv0 = CR(r0 - 1), gv1 = r0,        gv2 = CR(r0 + 1);
    const int gv3 = CR(r0 + 2), gv4 = CR(r0 + 3), gv5 = CR(r0 + 4);
    const int ou0 = CR(r0 - 2) * LONN + cb, ou1 = gv0 * LONN + cb;
    const int ou2 = r0 * LONN + cb,         ou3 = gv2 * LONN + cb;
    const int ou4 = gv3 * LONN + cb,        ou5 = gv4 * LONN + cb;
    const int ou6 = gv5 * LONN + cb,        ou7 = CR(r0 + 5) * LONN + cb;
    const int ov0 = ou1, ov1 = ou2, ov2 = ou3, ov3 = ou4, ov4 = ou5, ov5 = ou6;
    #undef CR

    const float* pu = u + (size_t)b * BATSTRIDE;
    const float* pv = v + (size_t)b * BATSTRIDE;
    const float idp = ws[WS_INVDP], i2dp = ws[WS_INV2DP];

    // per-vort-row scales (WG-uniform except eC0/eC1 lane factor)
    const float eC0 = e0 ? INV_DLON : INV_2DLON;
    const float eC1 = e1 ? INV_DLON : INV_2DLON;
    #define SRV(g) ((((g) == 0) || ((g) == LATN - 1)) ? INV_DLAT * INV_R : INV_2DLAT * INV_R)
    const float srv0 = SRV(gv0), srv1 = SRV(gv1), srv2 = SRV(gv2);
    const float srv3 = SRV(gv3), srv4 = SRV(gv4), srv5 = SRV(gv5);
    #undef SRV
    const float ix0 = ws[WS_INVDX + gv0], ix1 = ws[WS_INVDX + gv1];
    const float ix2 = ws[WS_INVDX + gv2], ix3 = ws[WS_INVDX + gv3];
    const float ix4 = ws[WS_INVDX + gv4], ix5 = ws[WS_INVDX + gv5];
    const float fc0 = ws[WS_FCOR + gv0], fc1 = ws[WS_FCOR + gv1];
    const float fc2 = ws[WS_FCOR + gv2], fc3 = ws[WS_FCOR + gv3];
    const float fc4 = ws[WS_FCOR + gv4], fc5 = ws[WS_FCOR + gv5];

    float vals[16];
    #pragma unroll
    for (int k = 0; k < 16; ++k) vals[k] = 0.f;
    float ssqt = 0.f, grad = 0.f;
    float2 wu0 = {0.f,0.f}, wu1 = {0.f,0.f}, wu2 = {0.f,0.f}, wu3 = {0.f,0.f};
    float2 wv0 = {0.f,0.f}, wv1 = {0.f,0.f}, wv2 = {0.f,0.f};
    float2 wv3 = {0.f,0.f}, wv4 = {0.f,0.f}, wv5 = {0.f,0.f};

    auto qgf = [&](float2 vo, float fc, float2 vpp) -> float2 {
        return make_float2(vo.x + fc + QG_COEF * vpp.x, vo.y + fc + QG_COEF * vpp.y);
    };
    auto vortf = [&](float2 vv, float2 ulo, float2 uhi, float ix, float sr) -> float2 {
        const float vL = __shfl_up(vv.y, 1), vR = __shfl_down(vv.x, 1);
        float2 r_;
        r_.x = (vv.y - (e0 ? vv.x : vL)) * (eC0 * ix) - (uhi.x - ulo.x) * sr;
        r_.y = ((e1 ? vv.y : vR) - vv.x) * (eC1 * ix) - (uhi.y - ulo.y) * sr;
        return r_;
    };
    // one output row: QM/QC/QP = qg rows K-1,K,K+1; scale row = vort stream K+1
    auto crow = [&](int k, float2 qm, float2 qc, float2 qp,
                    float sr, float ix, float mk0, float mk1) {
        const float qx = qc.x * mk0, qy = qc.y * mk1;
        vals[k] += qx + qy;
        ssqt += qx * qx + qy * qy;
        const float2 gl = sm2(qp, qm, sr);
        const float qL = __shfl_up(qc.y, 1), qR = __shfl_down(qc.x, 1);
        const float gnx = (qc.y - (e0 ? qc.x : qL)) * (eC0 * ix);
        const float gny = ((e1 ? qc.y : qR) - qc.x) * (eC1 * ix);
        grad += mk0 * (gl.x * gl.x + gnx * gnx) + mk1 * (gl.y * gl.y + gny * gny);
    };

    // rolling state ONLY (R8 lesson: NO level-indexed arrays -> no scratch)
    float2 vo2_0, vo1_0, pa_0, pb_0;
    float2 vo2_1, vo1_1, pa_1, pb_1;
    float2 vo2_2, vo1_2, pa_2, pb_2;
    float2 vo2_3, vo1_3, pa_3, pb_3;
    float2 vo2_4, vo1_4, pa_4, pb_4;
    float2 vo2_5, vo1_5, pa_5, pb_5;

    #define PIPE(S, CO, FC, QOUT) do {                                           \
        if (l == 0) { vo1_##S = (CO); }                                          \
        else if (l == 1) {                                                       \
            pb_##S = sm2((CO), vo1_##S, idp);                                    \
            vo2_##S = vo1_##S; vo1_##S = (CO);                                   \
        } else {                                                                 \
            const float2 pn_ = sm2((CO), vo2_##S, i2dp);                         \
            QOUT = (l == 2) ? qgf(vo2_##S, (FC), sm2(pn_, pb_##S, idp))          \
                            : qgf(vo2_##S, (FC), sm2(pn_, pa_##S, i2dp));        \
            pa_##S = pb_##S; pb_##S = pn_;                                       \
            vo2_##S = vo1_##S; vo1_##S = (CO);                                   \
        }                                                                        \
    } while (0)

    #pragma unroll
    for (int l = 0; l < NLEV; ++l) {
        const float wl = ws[WS_W + l];               // uniform -> SGPR
        const float2 u0 = ld2(pu + ou0), u1 = ld2(pu + ou1), u2 = ld2(pu + ou2);
        const float2 u3 = ld2(pu + ou3), u4 = ld2(pu + ou4), u5 = ld2(pu + ou5);
        const float2 u6 = ld2(pu + ou6), u7 = ld2(pu + ou7);
        const float2 v0 = ld2(pv + ov0), v1 = ld2(pv + ov1), v2 = ld2(pv + ov2);
        const float2 v3 = ld2(pv + ov3), v4 = ld2(pv + ov4), v5 = ld2(pv + ov5);

        wu0.x = fmaf(wl, u2.x, wu0.x);  wu0.y = fmaf(wl, u2.y, wu0.y);
        wu1.x = fmaf(wl, u3.x, wu1.x);  wu1.y = fmaf(wl, u3.y, wu1.y);
        wu2.x = fmaf(wl, u4.x, wu2.x);  wu2.y = fmaf(wl, u4.y, wu2.y);
        wu3.x = fmaf(wl, u5.x, wu3.x);  wu3.y = fmaf(wl, u5.y, wu3.y);
        wv0.x = fmaf(wl, v0.x, wv0.x);  wv0.y = fmaf(wl, v0.y, wv0.y);
        wv1.x = fmaf(wl, v1.x, wv1.x);  wv1.y = fmaf(wl, v1.y, wv1.y);
        wv2.x = fmaf(wl, v2.x, wv2.x);  wv2.y = fmaf(wl, v2.y, wv2.y);
        wv3.x = fmaf(wl, v3.x, wv3.x);  wv3.y = fmaf(wl, v3.y, wv3.y);
        wv4.x = fmaf(wl, v4.x, wv4.x);  wv4.y = fmaf(wl, v4.y, wv4.y);
        wv5.x = fmaf(wl, v5.x, wv5.x);  wv5.y = fmaf(wl, v5.y, wv5.y);

        // vort stream j uses v_j and u_j, u_{j+2}
        float2 co0 = vortf(v0, u0, u2, ix0, srv0);
        const float2 co1 = vortf(v1, u1, u3, ix1, srv1);
        float2 co2 = vortf(v2, u2, u4, ix2, srv2);
        float2 co3 = vortf(v3, u3, u5, ix3, srv3);
        float2 co4 = vortf(v4, u4, u6, ix4, srv4);
        float2 co5 = vortf(v5, u5, u7, ix5, srv5);
        if (rTop) co0 = co1;                         // clamped halo row == own row
        if (rBot) { co2 = co1; co3 = co1; co4 = co1; co5 = co1; }

        float2 q0, q1, q2, q3, q4, q5;
        PIPE(0, co0, fc0, q0);  PIPE(1, co1, fc1, q1);  PIPE(2, co2, fc2, q2);
        PIPE(3, co3, fc3, q3);  PIPE(4, co4, fc4, q4);  PIPE(5, co5, fc5, q5);
        if (l >= 2) {
            crow(l - 2, q0, q1, q2, srv1, ix1, m0,  m1);
            crow(l - 2, q1, q2, q3, srv2, ix2, m10, m11);
            crow(l - 2, q2, q3, q4, srv3, ix3, m20, m21);
            crow(l - 2, q3, q4, q5, srv4, ix4, m30, m31);
        }
        pu += SLICE; pv += SLICE;                    // uniform SALU bump
    }
    #undef PIPE
    // tail: vp1[12] one-sided; emit qg[11], qg[12]
    {
        #define TAIL(S, FC, Q11, Q12) do {                                       \
            const float2 p12_ = sm2(vo1_##S, vo2_##S, idp);                      \
            Q11 = qgf(vo2_##S, (FC), sm2(p12_, pa_##S, i2dp));                   \
            Q12 = qgf(vo1_##S, (FC), sm2(p12_, pb_##S, idp));                    \
        } while (0)
        float2 a0, b0, a1, b1, a2, b2, a3, b3, a4, b4, a5, b5;
        TAIL(0, fc0, a0, b0);  TAIL(1, fc1, a1, b1);  TAIL(2, fc2, a2, b2);
        TAIL(3, fc3, a3, b3);  TAIL(4, fc4, a4, b4);  TAIL(5, fc5, a5, b5);
        #undef TAIL
        crow(11, a0, a1, a2, srv1, ix1, m0,  m1);
        crow(11, a1, a2, a3, srv2, ix2, m10, m11);
        crow(11, a2, a3, a4, srv3, ix3, m20, m21);
        crow(11, a3, a4, a5, srv4, ix4, m30, m31);
        crow(12, b0, b1, b2, srv1, ix1, m0,  m1);
        crow(12, b1, b2, b3, srv2, ix2, m10, m11);
        crow(12, b2, b3, b4, srv3, ix3, m20, m21);
        crow(12, b3, b4, b5, srv4, ix4, m30, m31);
    }

    vals[13] += ssqt;
    vals[14] += grad;
    // mass: du/dx in-lane/shfl + edge selects; dv/dy via wv streams (clamped -> exact edges)
    {
        #define MROW(WU, WVLO, WVHI, SR, IX, MK0, MK1) do {                      \
            const float uL = __shfl_up((WU).y, 1), uR = __shfl_down((WU).x, 1);  \
            const float cdx = ((WU).y - (e0 ? (WU).x : uL)) * (eC0 * (IX))       \
                            + ((WVHI).x - (WVLO).x) * (SR);                      \
            const float cdy = ((e1 ? (WU).y : uR) - (WU).x) * (eC1 * (IX))       \
                            + ((WVHI).y - (WVLO).y) * (SR);                      \
            vals[15] += (MK0) * cdx * cdx + (MK1) * cdy * cdy;                   \
        } while (0)
        MROW(wu0, wv0, wv2, srv1, ix1, m0,  m1);
        MROW(wu1, wv1, wv3, srv2, ix2, m10, m11);
        MROW(wu2, wv2, wv4, srv3, ix3, m20, m21);
        MROW(wu3, wv3, wv5, srv4, ix4, m30, m31);
        #undef MROW
    }

    // ---- reduction: 4-step 16-lane-group butterfly + LDS transpose (16 values) ----
    #pragma unroll
    for (int k = 0; k < 16; ++k) {
        float x = vals[k];
        x += __shfl_xor(x, 8, 64);
        x += __shfl_xor(x, 4, 64);
        x += __shfl_xor(x, 2, 64);
        x += __shfl_xor(x, 1, 64);
        vals[k] = x;
    }
    const int g = tid >> 4, k16 = tid & 15;
    float myv = vals[0];
    #pragma unroll
    for (int k = 1; k < 16; ++k) if (k16 == k) myv = vals[k];   // static-index select
    red[g][k16] = myv;
    __syncthreads();

    if (tid < 16) {
        const int k = tid;
        float s = 0.f;
        #pragma unroll
        for (int g2 = 0; g2 < 16; ++g2) s += red[g2][k];
        int target;
        if (k < 13)       target = ACC_SUM + b * 13 + k;
        else if (k == 13) target = ACC_SSQ + b;
        else if (k == 14) target = ACC_GRAD;
        else              target = ACC_MASS;
        const int bank = (b * NWGX + blockIdx.x) & (NBANK - 1);
        atomicAdd(&ws[WS_ACC + bank * BANKSTRIDE + target], s);
    }
}

// ---------------- finalize: sum banks, apply formulas ----------------
__global__ void pl_finalize_kernel(const float* __restrict__ ws, float* __restrict__ out) {
    __shared__ float tot[N_ACC];
    const int t = threadIdx.x;
    if (t < N_ACC) {
        float s = 0.f;
        for (int bk = 0; bk < NBANK; ++bk) s += ws[WS_ACC + bk * BANKSTRIDE + t];
        tot[t] = s;
    }
    __syncthreads();
    if (t == 0) {
        const float N = (float)SLICE;
        float s2 = 0.f;
        for (int s = 0; s < 2 * NLEV; ++s) s2 += tot[ACC_SUM + s] * tot[ACC_SUM + s];
        const float ssq = tot[ACC_SSQ + 0] + tot[ACC_SSQ + 1];
        float vmean = (ssq - s2 / N) / (N - 1.0f) * (1.0f / (2.0f * NLEV));
        float gmean = tot[ACC_GRAD] / (float)(NBATCH * NLEV * SLICE);
        float mmean = tot[ACC_MASS] / (float)(NBATCH * SLICE);
        out[0] = vmean + 0.1f * gmean + mmean;          // spectra_loss statically 0
    }
}

extern "C" void kernel_launch(void* const* d_in, const int* in_sizes, int n_in,
                              void* d_out, int out_size, void* d_ws, size_t ws_size,
                              hipStream_t stream) {
    const float* u    = (const float*)d_in[0];
    const float* v    = (const float*)d_in[1];
    const float* plev = (const float*)d_in[2];
    float* ws  = (float*)d_ws;
    float* out = (float*)d_out;

    hipLaunchKernelGGL(pl_setup_kernel, dim3(1), dim3(1024), 0, stream, plev, ws);
    hipLaunchKernelGGL(pl_rc42_kernel, dim3(NWGX, NBATCH), dim3(256), 0, stream, u, v, ws);
    hipLaunchKernelGGL(pl_finalize_kernel, dim3(1), dim3(64), 0, stream, ws, out);
}